// Round 1
// baseline (821.445 us; speedup 1.0000x reference)
//
#include <hip/hip_runtime.h>
#include <math.h>

#define NUM_TAGS 20000
#define BATCH 64
#define H4 1024
#define HD 256
#define NT1 20001   // NUM_TAGS + 1

__device__ __forceinline__ float gelu_exact(float x) {
    return 0.5f * x * (1.0f + erff(x * 0.7071067811865476f));
}

// ---------------- counts: scatter with per-(b,f) dedup ----------------
__global__ __launch_bounds__(256) void k_scatter(const int* __restrict__ tags,
                                                 int* __restrict__ counts) {
    int g = blockIdx.x * 256 + threadIdx.x;  // 0..8191  (b,f)
    int b = g >> 7;
    const int* tp = tags + ((size_t)g << 4);
    int t[16];
#pragma unroll
    for (int i = 0; i < 16; ++i) t[i] = tp[i];
#pragma unroll
    for (int i = 0; i < 16; ++i) {
        bool dup = false;
        for (int j = 0; j < i; ++j) dup = dup || (t[j] == t[i]);
        if (!dup) atomicAdd(&counts[(size_t)b * NUM_TAGS + t[i]], 1);
    }
}

// ---------------- LN over counts -> y (row 0 of y is fc/100) ----------------
__global__ __launch_bounds__(256) void k_ln1(const int* __restrict__ counts,
                                             const float* __restrict__ fc,
                                             const float* __restrict__ lng,
                                             const float* __restrict__ lnb,
                                             float* __restrict__ y) {
    int b = blockIdx.x;
    int tid = threadIdx.x;
    const int* crow = counts + (size_t)b * NUM_TAGS;
    float s = 0.f, s2 = 0.f;
    for (int t = tid; t < NUM_TAGS; t += 256) {
        float c = (float)crow[t];
        s += c; s2 += c * c;
    }
#pragma unroll
    for (int off = 32; off > 0; off >>= 1) {
        s  += __shfl_down(s, off);
        s2 += __shfl_down(s2, off);
    }
    __shared__ float ls[4], ls2[4], smu, srs;
    int wave = tid >> 6;
    if ((tid & 63) == 0) { ls[wave] = s; ls2[wave] = s2; }
    __syncthreads();
    if (tid == 0) {
        float S  = ls[0] + ls[1] + ls[2] + ls[3];
        float S2 = ls2[0] + ls2[1] + ls2[2] + ls2[3];
        float mu = S / (float)NUM_TAGS;
        float var = S2 / (float)NUM_TAGS - mu * mu;
        smu = mu;
        srs = rsqrtf(var + 1e-5f);
    }
    __syncthreads();
    float mu = smu, rs = srs;
    float* yrow = y + (size_t)b * NT1;
    if (tid == 0) yrow[0] = fc[b] * 0.01f;
    for (int t = tid; t < NUM_TAGS; t += 256) {
        float c = (float)crow[t];
        yrow[1 + t] = (c - mu) * rs * lng[t] + lnb[t];
    }
}

// ---------------- init dec rows with bd2 (so GEMM5 atomics land on bias) ----
__global__ __launch_bounds__(256) void k_initdec(float* __restrict__ dec,
                                                 const float* __restrict__ bd2) {
    int n = blockIdx.x * 256 + threadIdx.x;
    if (n < NT1) dec[(size_t)blockIdx.y * NT1 + n] = bd2[n];
}

// ---------------- generic split-K SGEMM: C[64,N] += A[64,K] @ W[K,N] --------
// block: 256 thr = 32 n-quads x 8 b-groups; tile 64 x 128; fp32 atomic out.
__global__ __launch_bounds__(256) void k_gemm(const float* __restrict__ A, int lda,
                                              const float* __restrict__ W, int ldw,
                                              float* __restrict__ C, int ldc,
                                              int N, int K, int kpb) {
    __shared__ __align__(16) float Yt[32 * 68];
    int tid = threadIdx.x;
    int tn = tid & 31, tb = tid >> 5;
    int n0 = blockIdx.x * 128;
    int n = n0 + tn * 4;
    int kstart = blockIdx.y * kpb;
    int kend = min(K, kstart + kpb);
    float acc[8][4];
#pragma unroll
    for (int i = 0; i < 8; ++i)
#pragma unroll
        for (int j = 0; j < 4; ++j) acc[i][j] = 0.f;

    bool fullN = (n0 + 128 <= N);
    bool vec4 = fullN && ((ldw & 3) == 0);

    for (int k0 = kstart; k0 < kend; k0 += 32) {
        __syncthreads();
#pragma unroll
        for (int r = 0; r < 8; ++r) {
            int idx = tid + 256 * r;
            int kk = idx & 31, b = idx >> 5;
            int gk = k0 + kk;
            Yt[kk * 68 + b] = (gk < kend) ? A[(size_t)b * lda + gk] : 0.f;
        }
        __syncthreads();
        for (int kk = 0; kk < 32; ++kk) {
            int gk = k0 + kk;
            if (gk >= kend) break;
            float4 wv;
            if (vec4) {
                wv = *(const float4*)(W + (size_t)gk * ldw + n);
            } else {
                const float* wr = W + (size_t)gk * ldw;
                wv.x = (n + 0 < N) ? wr[n + 0] : 0.f;
                wv.y = (n + 1 < N) ? wr[n + 1] : 0.f;
                wv.z = (n + 2 < N) ? wr[n + 2] : 0.f;
                wv.w = (n + 3 < N) ? wr[n + 3] : 0.f;
            }
            const float4 ya = *(const float4*)&Yt[kk * 68 + tb * 8];
            const float4 yb = *(const float4*)&Yt[kk * 68 + tb * 8 + 4];
            float ys[8] = {ya.x, ya.y, ya.z, ya.w, yb.x, yb.y, yb.z, yb.w};
#pragma unroll
            for (int i = 0; i < 8; ++i) {
                acc[i][0] = fmaf(ys[i], wv.x, acc[i][0]);
                acc[i][1] = fmaf(ys[i], wv.y, acc[i][1]);
                acc[i][2] = fmaf(ys[i], wv.z, acc[i][2]);
                acc[i][3] = fmaf(ys[i], wv.w, acc[i][3]);
            }
        }
    }
#pragma unroll
    for (int i = 0; i < 8; ++i) {
        int row = tb * 8 + i;
#pragma unroll
        for (int j = 0; j < 4; ++j) {
            int nn = n + j;
            if (nn < N) atomicAdd(&C[(size_t)row * ldc + nn], acc[i][j]);
        }
    }
}

// ---------------- epilogues ----------------
// gelu(h1 + b1) then LayerNorm(ln2_g, ln2_b) -> h2.  one block per row.
__global__ __launch_bounds__(256) void k_gelu_ln2(const float* __restrict__ h1,
                                                  const float* __restrict__ b1,
                                                  const float* __restrict__ lng,
                                                  const float* __restrict__ lnb,
                                                  float* __restrict__ h2) {
    int b = blockIdx.x, tid = threadIdx.x;
    float v[4];
    float s = 0.f, s2 = 0.f;
#pragma unroll
    for (int j = 0; j < 4; ++j) {
        int nidx = tid + 256 * j;
        float x = h1[b * H4 + nidx] + b1[nidx];
        float g = gelu_exact(x);
        v[j] = g;
        s += g; s2 += g * g;
    }
#pragma unroll
    for (int off = 32; off > 0; off >>= 1) {
        s  += __shfl_down(s, off);
        s2 += __shfl_down(s2, off);
    }
    __shared__ float ls[4], ls2[4], smu, srs;
    int wave = tid >> 6;
    if ((tid & 63) == 0) { ls[wave] = s; ls2[wave] = s2; }
    __syncthreads();
    if (tid == 0) {
        float S  = ls[0] + ls[1] + ls[2] + ls[3];
        float S2 = ls2[0] + ls2[1] + ls2[2] + ls2[3];
        float mu = S / (float)H4;
        float var = S2 / (float)H4 - mu * mu;
        smu = mu;
        srs = rsqrtf(var + 1e-5f);
    }
    __syncthreads();
    float mu = smu, rs = srs;
#pragma unroll
    for (int j = 0; j < 4; ++j) {
        int nidx = tid + 256 * j;
        h2[b * H4 + nidx] = (v[j] - mu) * rs * lng[nidx] + lnb[nidx];
    }
}

__global__ __launch_bounds__(256) void k_bias_gelu(float* __restrict__ buf,
                                                   const float* __restrict__ bias,
                                                   int mask, int total) {
    int idx = blockIdx.x * 256 + threadIdx.x;
    if (idx < total) buf[idx] = gelu_exact(buf[idx] + bias[idx & mask]);
}

__global__ __launch_bounds__(256) void k_bias(float* __restrict__ buf,
                                              const float* __restrict__ bias,
                                              int mask, int total) {
    int idx = blockIdx.x * 256 + threadIdx.x;
    if (idx < total) buf[idx] += bias[idx & mask];
}

// ---------------- launch ----------------
extern "C" void kernel_launch(void* const* d_in, const int* in_sizes, int n_in,
                              void* d_out, int out_size, void* d_ws, size_t ws_size,
                              hipStream_t stream) {
    (void)in_sizes; (void)n_in; (void)out_size; (void)ws_size;
    const int*   tags  = (const int*)d_in[0];
    const float* fc    = (const float*)d_in[1];
    const float* ln_g  = (const float*)d_in[2];
    const float* ln_b  = (const float*)d_in[3];
    const float* w1    = (const float*)d_in[4];
    const float* b1    = (const float*)d_in[5];
    const float* ln2_g = (const float*)d_in[6];
    const float* ln2_b = (const float*)d_in[7];
    const float* we1   = (const float*)d_in[8];
    const float* be1   = (const float*)d_in[9];
    const float* we2   = (const float*)d_in[10];
    const float* be2   = (const float*)d_in[11];
    const float* wd1   = (const float*)d_in[12];
    const float* bd1   = (const float*)d_in[13];
    const float* wd2   = (const float*)d_in[14];
    const float* bd2   = (const float*)d_in[15];

    float* out = (float*)d_out;
    float* y   = out;                              // 64*20001
    float* enc = out + (size_t)BATCH * NT1;        // 64*256
    float* dec = enc + BATCH * HD;                 // 64*20001

    char* ws = (char*)d_ws;
    int*   counts = (int*)ws;                                       // 64*20000
    float* h1 = (float*)(ws + (size_t)BATCH * NUM_TAGS * 4);        // 64*1024
    float* h2 = h1 + BATCH * H4;
    float* g2 = h2 + BATCH * H4;
    float* dd = g2 + BATCH * H4;

    hipMemsetAsync(counts, 0, (size_t)BATCH * NUM_TAGS * 4, stream);
    hipMemsetAsync(h1, 0, BATCH * H4 * 4, stream);
    hipMemsetAsync(g2, 0, BATCH * H4 * 4, stream);
    hipMemsetAsync(dd, 0, BATCH * H4 * 4, stream);
    hipMemsetAsync(enc, 0, BATCH * HD * 4, stream);

    k_scatter<<<32, 256, 0, stream>>>(tags, counts);
    k_initdec<<<dim3(79, 64), 256, 0, stream>>>(dec, bd2);
    k_ln1<<<64, 256, 0, stream>>>(counts, fc, ln_g, ln_b, y);

    // GEMM1: h1 += y[64,20001] @ w1[20001,1024]
    k_gemm<<<dim3(8, 64), 256, 0, stream>>>(y, NT1, w1, H4, h1, H4, H4, NT1, 313);
    k_gelu_ln2<<<64, 256, 0, stream>>>(h1, b1, ln2_g, ln2_b, h2);

    // GEMM2: g2 += h2 @ we1[1024,1024]
    k_gemm<<<dim3(8, 16), 256, 0, stream>>>(h2, H4, we1, H4, g2, H4, H4, H4, 64);
    k_bias_gelu<<<256, 256, 0, stream>>>(g2, be1, 1023, BATCH * H4);

    // GEMM3: enc += g2 @ we2[1024,256]
    k_gemm<<<dim3(2, 32), 256, 0, stream>>>(g2, H4, we2, HD, enc, HD, HD, H4, 32);
    k_bias<<<64, 256, 0, stream>>>(enc, be2, 255, BATCH * HD);

    // GEMM4: dd += enc @ wd1[256,1024]
    k_gemm<<<dim3(8, 8), 256, 0, stream>>>(enc, HD, wd1, H4, dd, H4, H4, HD, 32);
    k_bias_gelu<<<256, 256, 0, stream>>>(dd, bd1, 1023, BATCH * H4);

    // GEMM5: dec += dd @ wd2[1024,20001]  (dec pre-loaded with bd2)
    k_gemm<<<dim3(157, 4), 256, 0, stream>>>(dd, H4, wd2, NT1, dec, NT1, NT1, H4, 256);
}

// Round 2
// 714.656 us; speedup vs baseline: 1.1494x; 1.1494x over previous
//
#include <hip/hip_runtime.h>
#include <math.h>

#define NUM_TAGS 20000
#define BATCH 64
#define H4 1024
#define HD 256
#define NT1 20001   // NUM_TAGS + 1

__device__ __forceinline__ float gelu_exact(float x) {
    return 0.5f * x * (1.0f + erff(x * 0.7071067811865476f));
}

// ---------------- counts: scatter with per-(b,f) dedup ----------------
__global__ __launch_bounds__(256) void k_scatter(const int* __restrict__ tags,
                                                 int* __restrict__ counts) {
    int g = blockIdx.x * 256 + threadIdx.x;  // 0..8191  (b,f)
    int b = g >> 7;
    const int* tp = tags + ((size_t)g << 4);
    int t[16];
#pragma unroll
    for (int i = 0; i < 16; ++i) t[i] = tp[i];
#pragma unroll
    for (int i = 0; i < 16; ++i) {
        bool dup = false;
        for (int j = 0; j < i; ++j) dup = dup || (t[j] == t[i]);
        if (!dup) atomicAdd(&counts[(size_t)b * NUM_TAGS + t[i]], 1);
    }
}

// ---------------- LN over counts -> y (row 0 of y is fc/100) ----------------
__global__ __launch_bounds__(256) void k_ln1(const int* __restrict__ counts,
                                             const float* __restrict__ fc,
                                             const float* __restrict__ lng,
                                             const float* __restrict__ lnb,
                                             float* __restrict__ y) {
    int b = blockIdx.x;
    int tid = threadIdx.x;
    const int* crow = counts + (size_t)b * NUM_TAGS;
    float s = 0.f, s2 = 0.f;
    for (int t = tid; t < NUM_TAGS; t += 256) {
        float c = (float)crow[t];
        s += c; s2 += c * c;
    }
#pragma unroll
    for (int off = 32; off > 0; off >>= 1) {
        s  += __shfl_down(s, off);
        s2 += __shfl_down(s2, off);
    }
    __shared__ float ls[4], ls2[4], smu, srs;
    int wave = tid >> 6;
    if ((tid & 63) == 0) { ls[wave] = s; ls2[wave] = s2; }
    __syncthreads();
    if (tid == 0) {
        float S  = ls[0] + ls[1] + ls[2] + ls[3];
        float S2 = ls2[0] + ls2[1] + ls2[2] + ls2[3];
        float mu = S / (float)NUM_TAGS;
        float var = S2 / (float)NUM_TAGS - mu * mu;
        smu = mu;
        srs = rsqrtf(var + 1e-5f);
    }
    __syncthreads();
    float mu = smu, rs = srs;
    float* yrow = y + (size_t)b * NT1;
    if (tid == 0) yrow[0] = fc[b] * 0.01f;
    for (int t = tid; t < NUM_TAGS; t += 256) {
        float c = (float)crow[t];
        yrow[1 + t] = (c - mu) * rs * lng[t] + lnb[t];
    }
}

// ---------------- init dec rows with bd2 (so GEMM5 atomics land on bias) ----
__global__ __launch_bounds__(256) void k_initdec(float* __restrict__ dec,
                                                 const float* __restrict__ bd2) {
    int n = blockIdx.x * 256 + threadIdx.x;
    if (n < NT1) dec[(size_t)blockIdx.y * NT1 + n] = bd2[n];
}

// ---------------- split-K SGEMM: C[64,N] += A[64,K] @ W[K,N] ----------------
// block: 256 thr = 32 n-quads x 8 row-groups; tile 64 x 128; fp32 atomic out.
// PATH 0: aligned float4 W loads (ldw % 4 == 0, full N tile)
// PATH 1: 4x dword W loads, clamped columns (odd ldw and/or N tail)
// Branch-free K handling: W row index clamped to K-1, A zero-padded in LDS.
// 8-deep software-pipelined W prefetch (8 x 16B in flight per thread).
template <int PATH>
__global__ __launch_bounds__(256, 4) void k_gemm(const float* __restrict__ A, int lda,
                                                 const float* __restrict__ W, int ldw,
                                                 float* __restrict__ C, int ldc,
                                                 int N, int K, int kpb) {
    __shared__ __align__(16) float Yt[32 * 68];
    const int tid = threadIdx.x;
    const int tn = tid & 31, tb = tid >> 5;
    const int n0 = blockIdx.x * 128;
    const int n  = n0 + tn * 4;
    const int kstart = blockIdx.y * kpb;
    const int kend   = min(K, kstart + kpb);

    float acc[8][4];
#pragma unroll
    for (int i = 0; i < 8; ++i)
#pragma unroll
        for (int j = 0; j < 4; ++j) acc[i][j] = 0.f;

    // clamped per-column indices for PATH 1
    const int nj0 = min(n + 0, N - 1);
    const int nj1 = min(n + 1, N - 1);
    const int nj2 = min(n + 2, N - 1);
    const int nj3 = min(n + 3, N - 1);

    for (int k0 = kstart; k0 < kend; k0 += 32) {
        __syncthreads();
        // stage A[0..63][k0..k0+31] -> Yt[kk][b], zero-padded past kend
        {
            int gk = k0 + tn;
            bool ok = (gk < kend);
#pragma unroll
            for (int r = 0; r < 8; ++r) {
                int b = tb + 8 * r;
                Yt[tn * 68 + b] = ok ? A[(size_t)b * lda + gk] : 0.f;
            }
        }
        __syncthreads();

        float4 w[8];
#pragma unroll
        for (int u = 0; u < 8; ++u) {
            const float* wr = W + (size_t)min(k0 + u, K - 1) * ldw;
            if (PATH == 0) {
                w[u] = *(const float4*)(wr + n);
            } else {
                w[u].x = wr[nj0]; w[u].y = wr[nj1]; w[u].z = wr[nj2]; w[u].w = wr[nj3];
            }
        }
#pragma unroll
        for (int kk = 0; kk < 32; ++kk) {
            float4 wc = w[0];
#pragma unroll
            for (int u = 0; u < 7; ++u) w[u] = w[u + 1];
            if (kk + 8 < 32) {
                const float* wr = W + (size_t)min(k0 + kk + 8, K - 1) * ldw;
                if (PATH == 0) {
                    w[7] = *(const float4*)(wr + n);
                } else {
                    w[7].x = wr[nj0]; w[7].y = wr[nj1]; w[7].z = wr[nj2]; w[7].w = wr[nj3];
                }
            }
            const float4 ya = *(const float4*)&Yt[kk * 68 + tb * 8];
            const float4 yb = *(const float4*)&Yt[kk * 68 + tb * 8 + 4];
            const float ys[8] = {ya.x, ya.y, ya.z, ya.w, yb.x, yb.y, yb.z, yb.w};
#pragma unroll
            for (int i = 0; i < 8; ++i) {
                acc[i][0] = fmaf(ys[i], wc.x, acc[i][0]);
                acc[i][1] = fmaf(ys[i], wc.y, acc[i][1]);
                acc[i][2] = fmaf(ys[i], wc.z, acc[i][2]);
                acc[i][3] = fmaf(ys[i], wc.w, acc[i][3]);
            }
        }
    }
#pragma unroll
    for (int i = 0; i < 8; ++i) {
        int row = tb * 8 + i;
#pragma unroll
        for (int j = 0; j < 4; ++j) {
            int nn = n + j;
            if (nn < N) atomicAdd(&C[(size_t)row * ldc + nn], acc[i][j]);
        }
    }
}

// ---------------- epilogues ----------------
__global__ __launch_bounds__(256) void k_gelu_ln2(const float* __restrict__ h1,
                                                  const float* __restrict__ b1,
                                                  const float* __restrict__ lng,
                                                  const float* __restrict__ lnb,
                                                  float* __restrict__ h2) {
    int b = blockIdx.x, tid = threadIdx.x;
    float v[4];
    float s = 0.f, s2 = 0.f;
#pragma unroll
    for (int j = 0; j < 4; ++j) {
        int nidx = tid + 256 * j;
        float x = h1[b * H4 + nidx] + b1[nidx];
        float g = gelu_exact(x);
        v[j] = g;
        s += g; s2 += g * g;
    }
#pragma unroll
    for (int off = 32; off > 0; off >>= 1) {
        s  += __shfl_down(s, off);
        s2 += __shfl_down(s2, off);
    }
    __shared__ float ls[4], ls2[4], smu, srs;
    int wave = tid >> 6;
    if ((tid & 63) == 0) { ls[wave] = s; ls2[wave] = s2; }
    __syncthreads();
    if (tid == 0) {
        float S  = ls[0] + ls[1] + ls[2] + ls[3];
        float S2 = ls2[0] + ls2[1] + ls2[2] + ls2[3];
        float mu = S / (float)H4;
        float var = S2 / (float)H4 - mu * mu;
        smu = mu;
        srs = rsqrtf(var + 1e-5f);
    }
    __syncthreads();
    float mu = smu, rs = srs;
#pragma unroll
    for (int j = 0; j < 4; ++j) {
        int nidx = tid + 256 * j;
        h2[b * H4 + nidx] = (v[j] - mu) * rs * lng[nidx] + lnb[nidx];
    }
}

__global__ __launch_bounds__(256) void k_bias_gelu(float* __restrict__ buf,
                                                   const float* __restrict__ bias,
                                                   int mask, int total) {
    int idx = blockIdx.x * 256 + threadIdx.x;
    if (idx < total) buf[idx] = gelu_exact(buf[idx] + bias[idx & mask]);
}

__global__ __launch_bounds__(256) void k_bias(float* __restrict__ buf,
                                              const float* __restrict__ bias,
                                              int mask, int total) {
    int idx = blockIdx.x * 256 + threadIdx.x;
    if (idx < total) buf[idx] += bias[idx & mask];
}

// ---------------- launch ----------------
extern "C" void kernel_launch(void* const* d_in, const int* in_sizes, int n_in,
                              void* d_out, int out_size, void* d_ws, size_t ws_size,
                              hipStream_t stream) {
    (void)in_sizes; (void)n_in; (void)out_size; (void)ws_size;
    const int*   tags  = (const int*)d_in[0];
    const float* fc    = (const float*)d_in[1];
    const float* ln_g  = (const float*)d_in[2];
    const float* ln_b  = (const float*)d_in[3];
    const float* w1    = (const float*)d_in[4];
    const float* b1    = (const float*)d_in[5];
    const float* ln2_g = (const float*)d_in[6];
    const float* ln2_b = (const float*)d_in[7];
    const float* we1   = (const float*)d_in[8];
    const float* be1   = (const float*)d_in[9];
    const float* we2   = (const float*)d_in[10];
    const float* be2   = (const float*)d_in[11];
    const float* wd1   = (const float*)d_in[12];
    const float* bd1   = (const float*)d_in[13];
    const float* wd2   = (const float*)d_in[14];
    const float* bd2   = (const float*)d_in[15];

    float* out = (float*)d_out;
    float* y   = out;                              // 64*20001
    float* enc = out + (size_t)BATCH * NT1;        // 64*256
    float* dec = enc + BATCH * HD;                 // 64*20001

    char* ws = (char*)d_ws;
    int*   counts = (int*)ws;                                       // 64*20000
    float* h1 = (float*)(ws + (size_t)BATCH * NUM_TAGS * 4);        // 64*1024
    float* h2 = h1 + BATCH * H4;
    float* g2 = h2 + BATCH * H4;
    float* dd = g2 + BATCH * H4;

    hipMemsetAsync(counts, 0, (size_t)BATCH * NUM_TAGS * 4, stream);
    hipMemsetAsync(h1, 0, BATCH * H4 * 4, stream);
    hipMemsetAsync(g2, 0, BATCH * H4 * 4, stream);
    hipMemsetAsync(dd, 0, BATCH * H4 * 4, stream);
    hipMemsetAsync(enc, 0, BATCH * HD * 4, stream);

    k_scatter<<<32, 256, 0, stream>>>(tags, counts);
    k_initdec<<<dim3(79, 64), 256, 0, stream>>>(dec, bd2);
    k_ln1<<<64, 256, 0, stream>>>(counts, fc, ln_g, ln_b, y);

    // GEMM1: h1 += y[64,20001] @ w1[20001,1024]   (1008 blocks, kpb=160)
    k_gemm<0><<<dim3(8, 126), 256, 0, stream>>>(y, NT1, w1, H4, h1, H4, H4, NT1, 160);
    k_gelu_ln2<<<64, 256, 0, stream>>>(h1, b1, ln2_g, ln2_b, h2);

    // GEMM2: g2 += h2 @ we1[1024,1024]   (256 blocks)
    k_gemm<0><<<dim3(8, 32), 256, 0, stream>>>(h2, H4, we1, H4, g2, H4, H4, H4, 32);
    k_bias_gelu<<<256, 256, 0, stream>>>(g2, be1, 1023, BATCH * H4);

    // GEMM3: enc += g2 @ we2[1024,256]   (64 blocks)
    k_gemm<0><<<dim3(2, 32), 256, 0, stream>>>(g2, H4, we2, HD, enc, HD, HD, H4, 32);
    k_bias<<<64, 256, 0, stream>>>(enc, be2, 255, BATCH * HD);

    // GEMM4: dd += enc @ wd1[256,1024]   (64 blocks)
    k_gemm<0><<<dim3(8, 8), 256, 0, stream>>>(enc, HD, wd1, H4, dd, H4, H4, HD, 32);
    k_bias_gelu<<<256, 256, 0, stream>>>(dd, bd1, 1023, BATCH * H4);

    // GEMM5: dec += dd @ wd2[1024,20001]  (628 blocks, odd ldw -> PATH 1)
    k_gemm<1><<<dim3(157, 4), 256, 0, stream>>>(dd, H4, wd2, NT1, dec, NT1, NT1, H4, 256);
}

// Round 3
// 531.550 us; speedup vs baseline: 1.5454x; 1.3445x over previous
//
#include <hip/hip_runtime.h>
#include <math.h>

#define NUM_TAGS 20000
#define BATCH 64
#define H4 1024
#define HD 256
#define NT1 20001   // NUM_TAGS + 1

__device__ __forceinline__ float gelu_exact(float x) {
    return 0.5f * x * (1.0f + erff(x * 0.7071067811865476f));
}

// ---------------- counts: scatter with per-(b,f) dedup ----------------
__global__ __launch_bounds__(256) void k_scatter(const int* __restrict__ tags,
                                                 int* __restrict__ counts) {
    int g = blockIdx.x * 256 + threadIdx.x;  // 0..8191  (b,f)
    int b = g >> 7;
    const int* tp = tags + ((size_t)g << 4);
    int t[16];
#pragma unroll
    for (int i = 0; i < 16; ++i) t[i] = tp[i];
#pragma unroll
    for (int i = 0; i < 16; ++i) {
        bool dup = false;
        for (int j = 0; j < i; ++j) dup = dup || (t[j] == t[i]);
        if (!dup) atomicAdd(&counts[(size_t)b * NUM_TAGS + t[i]], 1);
    }
}

// ---------------- LN1 phase A: partial stats, grid (8, 64) ----------------
__global__ __launch_bounds__(256) void k_ln1_stats(const int* __restrict__ counts,
                                                   float* __restrict__ stats) {
    int b = blockIdx.y, c = blockIdx.x, tid = threadIdx.x;
    const int* crow = counts + (size_t)b * NUM_TAGS;
    int lo = c * 2500, hi = lo + 2500;
    float s = 0.f, s2 = 0.f;
    for (int t = lo + tid; t < hi; t += 256) {
        float v = (float)crow[t];
        s += v; s2 += v * v;
    }
#pragma unroll
    for (int off = 32; off > 0; off >>= 1) {
        s  += __shfl_down(s, off);
        s2 += __shfl_down(s2, off);
    }
    __shared__ float ls[4], ls2[4];
    int wave = tid >> 6;
    if ((tid & 63) == 0) { ls[wave] = s; ls2[wave] = s2; }
    __syncthreads();
    if (tid == 0) {
        stats[(b * 8 + c) * 2 + 0] = ls[0] + ls[1] + ls[2] + ls[3];
        stats[(b * 8 + c) * 2 + 1] = ls2[0] + ls2[1] + ls2[2] + ls2[3];
    }
}

// ---------------- LN1 phase B: apply, grid (8, 64) ----------------
__global__ __launch_bounds__(256) void k_ln1_apply(const int* __restrict__ counts,
                                                   const float* __restrict__ fc,
                                                   const float* __restrict__ lng,
                                                   const float* __restrict__ lnb,
                                                   const float* __restrict__ stats,
                                                   float* __restrict__ y) {
    int b = blockIdx.y, c = blockIdx.x, tid = threadIdx.x;
    float S = 0.f, S2 = 0.f;
#pragma unroll
    for (int i = 0; i < 8; ++i) {
        S  += stats[(b * 8 + i) * 2 + 0];
        S2 += stats[(b * 8 + i) * 2 + 1];
    }
    float mu = S / (float)NUM_TAGS;
    float var = S2 / (float)NUM_TAGS - mu * mu;
    float rs = rsqrtf(var + 1e-5f);
    const int* crow = counts + (size_t)b * NUM_TAGS;
    float* yrow = y + (size_t)b * NT1;
    if (c == 0 && tid == 0) yrow[0] = fc[b] * 0.01f;
    int lo = c * 2500, hi = lo + 2500;
    for (int t = lo + tid; t < hi; t += 256) {
        float v = (float)crow[t];
        yrow[1 + t] = (v - mu) * rs * lng[t] + lnb[t];
    }
}

// ---------------- split-K GEMM to partial buffer (no atomics) --------------
// C_partial[slice][64][128] = A[64, kslice] @ W[kslice, 128cols]
// 128 threads: thread = (tn 0..15)x(tb 0..7), owns 8 rows x 8 cols.
// A and W both staged in LDS (W loaded exactly once per block).
// PATH 0: aligned float4 W loads; PATH 1: scalar W loads w/ clamped cols.
template <int PATH>
__global__ __launch_bounds__(128, 3) void k_gemm(const float* __restrict__ A, int lda,
                                                 const float* __restrict__ W, int ldw,
                                                 float* __restrict__ P,
                                                 int N, int K, int kpb, int KS) {
    __shared__ __align__(16) float As[32 * 68];    // [kk][row], pad 68
    __shared__ __align__(16) float Ws[32 * 128];   // [kk][col]
    const int tid = threadIdx.x;
    const int tn = tid & 15, tb = tid >> 4;
    const int n0 = blockIdx.x * 128;
    const int kstart = blockIdx.y * kpb;
    const int kend = min(K, kstart + kpb);
    const int nchunk = (kend > kstart) ? ((kend - kstart + 31) >> 5) : 0;

    float acc[8][8];
#pragma unroll
    for (int i = 0; i < 8; ++i)
#pragma unroll
        for (int j = 0; j < 8; ++j) acc[i][j] = 0.f;

    float a_r[16];
    float4 w_r[8];

#define LOAD_CHUNK(k0)                                                          \
    {                                                                           \
        _Pragma("unroll")                                                       \
        for (int u = 0; u < 16; ++u) {                                          \
            int idx = tid + 128 * u;                                            \
            int kk = idx & 31, row = idx >> 5;                                  \
            int gk = (k0) + kk;                                                 \
            float v = A[(size_t)row * lda + min(gk, K - 1)];                    \
            a_r[u] = (gk < kend) ? v : 0.f;                                     \
        }                                                                       \
        _Pragma("unroll")                                                       \
        for (int u = 0; u < 8; ++u) {                                           \
            int f4 = tid + 128 * u;                                             \
            int row = f4 >> 5, col4 = f4 & 31;                                  \
            int kr = min((k0) + row, K - 1);                                    \
            if (PATH == 0) {                                                    \
                w_r[u] = *(const float4*)(W + (size_t)kr * ldw + n0 + col4 * 4);\
            } else {                                                            \
                const float* wr = W + (size_t)kr * ldw;                         \
                int nb = n0 + col4 * 4;                                         \
                w_r[u].x = wr[min(nb + 0, N - 1)];                              \
                w_r[u].y = wr[min(nb + 1, N - 1)];                              \
                w_r[u].z = wr[min(nb + 2, N - 1)];                              \
                w_r[u].w = wr[min(nb + 3, N - 1)];                              \
            }                                                                   \
        }                                                                       \
    }

    if (nchunk > 0) LOAD_CHUNK(kstart);
    for (int c = 0; c < nchunk; ++c) {
        __syncthreads();
#pragma unroll
        for (int u = 0; u < 16; ++u) {
            int idx = tid + 128 * u;
            int kk = idx & 31, row = idx >> 5;
            As[kk * 68 + row] = a_r[u];
        }
#pragma unroll
        for (int u = 0; u < 8; ++u) {
            int f4 = tid + 128 * u;
            int row = f4 >> 5, col4 = f4 & 31;
            *(float4*)&Ws[row * 128 + col4 * 4] = w_r[u];
        }
        __syncthreads();
        if (c + 1 < nchunk) LOAD_CHUNK(kstart + 32 * (c + 1));
#pragma unroll 8
        for (int kk = 0; kk < 32; ++kk) {
            const float4 a0 = *(const float4*)&As[kk * 68 + tb * 8];
            const float4 a1 = *(const float4*)&As[kk * 68 + tb * 8 + 4];
            const float4 w0 = *(const float4*)&Ws[kk * 128 + tn * 8];
            const float4 w1 = *(const float4*)&Ws[kk * 128 + tn * 8 + 4];
            const float av[8] = {a0.x, a0.y, a0.z, a0.w, a1.x, a1.y, a1.z, a1.w};
            const float wv[8] = {w0.x, w0.y, w0.z, w0.w, w1.x, w1.y, w1.z, w1.w};
#pragma unroll
            for (int i = 0; i < 8; ++i)
#pragma unroll
                for (int j = 0; j < 8; ++j)
                    acc[i][j] = fmaf(av[i], wv[j], acc[i][j]);
        }
    }
#undef LOAD_CHUNK

    float* Pp = P + ((size_t)blockIdx.x * KS + blockIdx.y) * 8192;
#pragma unroll
    for (int i = 0; i < 8; ++i) {
        int row = tb * 8 + i;
        float4 v0 = {acc[i][0], acc[i][1], acc[i][2], acc[i][3]};
        float4 v1 = {acc[i][4], acc[i][5], acc[i][6], acc[i][7]};
        *(float4*)&Pp[row * 128 + tn * 8]     = v0;
        *(float4*)&Pp[row * 128 + tn * 8 + 4] = v1;
    }
}

// ---------------- reduce partials + bias (+gelu) ----------------
// grid: (ceil(N/256), 64); out[b*ldo + n] = act(sum_p P[(nb*KS+p)][b][col] + bias[n])
template <bool GELU>
__global__ __launch_bounds__(256) void k_reduce(const float* __restrict__ P, int KS,
                                                const float* __restrict__ bias,
                                                float* __restrict__ out, int ldo, int N) {
    int b = blockIdx.y;
    int n = blockIdx.x * 256 + threadIdx.x;
    if (n >= N) return;
    int nb = n >> 7, col = n & 127;
    const float* p = P + (size_t)nb * KS * 8192 + b * 128 + col;
    float s0 = 0.f, s1 = 0.f, s2 = 0.f, s3 = 0.f;
    int k = 0;
    for (; k + 3 < KS; k += 4) {
        s0 += p[(size_t)(k + 0) * 8192];
        s1 += p[(size_t)(k + 1) * 8192];
        s2 += p[(size_t)(k + 2) * 8192];
        s3 += p[(size_t)(k + 3) * 8192];
    }
    for (; k < KS; ++k) s0 += p[(size_t)k * 8192];
    float s = (s0 + s1) + (s2 + s3) + bias[n];
    if (GELU) s = gelu_exact(s);
    out[(size_t)b * ldo + n] = s;
}

// ---------------- LN2: one block per row (1024 cols) ----------------
__global__ __launch_bounds__(256) void k_ln2(const float* __restrict__ g1,
                                             const float* __restrict__ lng,
                                             const float* __restrict__ lnb,
                                             float* __restrict__ h2) {
    int b = blockIdx.x, tid = threadIdx.x;
    float v[4];
    float s = 0.f, s2 = 0.f;
#pragma unroll
    for (int j = 0; j < 4; ++j) {
        int nidx = tid + 256 * j;
        float x = g1[b * H4 + nidx];
        v[j] = x;
        s += x; s2 += x * x;
    }
#pragma unroll
    for (int off = 32; off > 0; off >>= 1) {
        s  += __shfl_down(s, off);
        s2 += __shfl_down(s2, off);
    }
    __shared__ float ls[4], ls2[4], smu, srs;
    int wave = tid >> 6;
    if ((tid & 63) == 0) { ls[wave] = s; ls2[wave] = s2; }
    __syncthreads();
    if (tid == 0) {
        float S  = ls[0] + ls[1] + ls[2] + ls[3];
        float S2 = ls2[0] + ls2[1] + ls2[2] + ls2[3];
        float mu = S / (float)H4;
        float var = S2 / (float)H4 - mu * mu;
        smu = mu;
        srs = rsqrtf(var + 1e-5f);
    }
    __syncthreads();
    float mu = smu, rs = srs;
#pragma unroll
    for (int j = 0; j < 4; ++j) {
        int nidx = tid + 256 * j;
        h2[b * H4 + nidx] = (v[j] - mu) * rs * lng[nidx] + lnb[nidx];
    }
}

// ---------------- launch ----------------
extern "C" void kernel_launch(void* const* d_in, const int* in_sizes, int n_in,
                              void* d_out, int out_size, void* d_ws, size_t ws_size,
                              hipStream_t stream) {
    (void)in_sizes; (void)n_in; (void)out_size;
    const int*   tags  = (const int*)d_in[0];
    const float* fc    = (const float*)d_in[1];
    const float* ln_g  = (const float*)d_in[2];
    const float* ln_b  = (const float*)d_in[3];
    const float* w1    = (const float*)d_in[4];
    const float* b1    = (const float*)d_in[5];
    const float* ln2_g = (const float*)d_in[6];
    const float* ln2_b = (const float*)d_in[7];
    const float* we1   = (const float*)d_in[8];
    const float* be1   = (const float*)d_in[9];
    const float* we2   = (const float*)d_in[10];
    const float* be2   = (const float*)d_in[11];
    const float* wd1   = (const float*)d_in[12];
    const float* bd1   = (const float*)d_in[13];
    const float* wd2   = (const float*)d_in[14];
    const float* bd2   = (const float*)d_in[15];

    float* out = (float*)d_out;
    float* y   = out;                              // 64*20001
    float* enc = out + (size_t)BATCH * NT1;        // 64*256
    float* dec = enc + BATCH * HD;                 // 64*20001

    char* ws = (char*)d_ws;
    size_t off = 0;
    int*   counts = (int*)(ws + off);   off += (size_t)BATCH * NUM_TAGS * 4;  // 5.12 MB
    float* stats  = (float*)(ws + off); off += 64 * 8 * 2 * 4;
    float* g1     = (float*)(ws + off); off += (size_t)BATCH * H4 * 4;
    float* h2     = (float*)(ws + off); off += (size_t)BATCH * H4 * 4;
    float* g2     = (float*)(ws + off); off += (size_t)BATCH * H4 * 4;
    float* dd     = (float*)(ws + off); off += (size_t)BATCH * H4 * 4;
    float* arena  = (float*)(ws + off);
    size_t avail  = (ws_size > off) ? (ws_size - off) : 0;

    // runtime split-K choice (ws_size is constant across calls -> deterministic)
    const size_t MB = 1024 * 1024;
    int KS1, KS5;
    if (avail >= 34 * MB)      { KS1 = 126; KS5 = 4; }
    else if (avail >= 21 * MB) { KS1 = 63;  KS5 = 4; }
    else if (avail >= 11 * MB) { KS1 = 31;  KS5 = 2; }
    else                       { KS1 = 31;  KS5 = 1; }
    int kpb1 = (((NT1 + KS1 - 1) / KS1) + 31) & ~31;
    int kpb5 = H4 / KS5;

    hipMemsetAsync(counts, 0, (size_t)BATCH * NUM_TAGS * 4, stream);
    k_scatter<<<32, 256, 0, stream>>>(tags, counts);
    k_ln1_stats<<<dim3(8, 64), 256, 0, stream>>>(counts, stats);
    k_ln1_apply<<<dim3(8, 64), 256, 0, stream>>>(counts, fc, ln_g, ln_b, stats, y);

    // GEMM1: y[64,20001] @ w1[20001,1024] -> partial
    k_gemm<0><<<dim3(8, KS1), 128, 0, stream>>>(y, NT1, w1, H4, arena, H4, NT1, kpb1, KS1);
    k_reduce<true><<<dim3(4, 64), 256, 0, stream>>>(arena, KS1, b1, g1, H4, H4);
    k_ln2<<<64, 256, 0, stream>>>(g1, ln2_g, ln2_b, h2);

    // GEMM2: h2 @ we1[1024,1024]
    k_gemm<0><<<dim3(8, 16), 128, 0, stream>>>(h2, H4, we1, H4, arena, H4, H4, 64, 16);
    k_reduce<true><<<dim3(4, 64), 256, 0, stream>>>(arena, 16, be1, g2, H4, H4);

    // GEMM3: g2 @ we2[1024,256]
    k_gemm<0><<<dim3(2, 16), 128, 0, stream>>>(g2, H4, we2, HD, arena, HD, H4, 64, 16);
    k_reduce<false><<<dim3(1, 64), 256, 0, stream>>>(arena, 16, be2, enc, HD, HD);

    // GEMM4: enc @ wd1[256,1024]
    k_gemm<0><<<dim3(8, 4), 128, 0, stream>>>(enc, HD, wd1, H4, arena, H4, HD, 64, 4);
    k_reduce<true><<<dim3(4, 64), 256, 0, stream>>>(arena, 4, bd1, dd, H4, H4);

    // GEMM5: dd @ wd2[1024,20001]  (odd ldw -> PATH 1)
    k_gemm<1><<<dim3(157, KS5), 128, 0, stream>>>(dd, H4, wd2, NT1, arena, NT1, H4, kpb5, KS5);
    k_reduce<false><<<dim3(79, 64), 256, 0, stream>>>(arena, KS5, bd2, dec, NT1, NT1);
}

// Round 4
// 373.686 us; speedup vs baseline: 2.1982x; 1.4224x over previous
//
#include <hip/hip_runtime.h>
#include <math.h>

#define NUM_TAGS 20000
#define BATCH 64
#define H4 1024
#define HD 256
#define NT1 20001   // NUM_TAGS + 1

__device__ __forceinline__ float gelu_exact(float x) {
    return 0.5f * x * (1.0f + erff(x * 0.7071067811865476f));
}

// ---------------- counts: scatter with per-(b,f) dedup ----------------
__global__ __launch_bounds__(256) void k_scatter(const int* __restrict__ tags,
                                                 int* __restrict__ counts) {
    int g = blockIdx.x * 256 + threadIdx.x;  // 0..8191  (b,f)
    int b = g >> 7;
    const int* tp = tags + ((size_t)g << 4);
    int t[16];
#pragma unroll
    for (int i = 0; i < 16; ++i) t[i] = tp[i];
#pragma unroll
    for (int i = 0; i < 16; ++i) {
        bool dup = false;
        for (int j = 0; j < i; ++j) dup = dup || (t[j] == t[i]);
        if (!dup) atomicAdd(&counts[(size_t)b * NUM_TAGS + t[i]], 1);
    }
}

// ---------------- LN1 phase A: partial stats, grid (8, 64) ----------------
__global__ __launch_bounds__(256) void k_ln1_stats(const int* __restrict__ counts,
                                                   float* __restrict__ stats) {
    int b = blockIdx.y, c = blockIdx.x, tid = threadIdx.x;
    const int* crow = counts + (size_t)b * NUM_TAGS;
    int lo = c * 2500, hi = lo + 2500;
    float s = 0.f, s2 = 0.f;
    for (int t = lo + tid; t < hi; t += 256) {
        float v = (float)crow[t];
        s += v; s2 += v * v;
    }
#pragma unroll
    for (int off = 32; off > 0; off >>= 1) {
        s  += __shfl_down(s, off);
        s2 += __shfl_down(s2, off);
    }
    __shared__ float ls[4], ls2[4];
    int wave = tid >> 6;
    if ((tid & 63) == 0) { ls[wave] = s; ls2[wave] = s2; }
    __syncthreads();
    if (tid == 0) {
        stats[(b * 8 + c) * 2 + 0] = ls[0] + ls[1] + ls[2] + ls[3];
        stats[(b * 8 + c) * 2 + 1] = ls2[0] + ls2[1] + ls2[2] + ls2[3];
    }
}

// ---------------- LN1 phase B: apply, grid (8, 64) ----------------
__global__ __launch_bounds__(256) void k_ln1_apply(const int* __restrict__ counts,
                                                   const float* __restrict__ fc,
                                                   const float* __restrict__ lng,
                                                   const float* __restrict__ lnb,
                                                   const float* __restrict__ stats,
                                                   float* __restrict__ y) {
    int b = blockIdx.y, c = blockIdx.x, tid = threadIdx.x;
    float S = 0.f, S2 = 0.f;
#pragma unroll
    for (int i = 0; i < 8; ++i) {
        S  += stats[(b * 8 + i) * 2 + 0];
        S2 += stats[(b * 8 + i) * 2 + 1];
    }
    float mu = S / (float)NUM_TAGS;
    float var = S2 / (float)NUM_TAGS - mu * mu;
    float rs = rsqrtf(var + 1e-5f);
    const int* crow = counts + (size_t)b * NUM_TAGS;
    float* yrow = y + (size_t)b * NT1;
    if (c == 0 && tid == 0) yrow[0] = fc[b] * 0.01f;
    int lo = c * 2500, hi = lo + 2500;
    for (int t = lo + tid; t < hi; t += 256) {
        float v = (float)crow[t];
        yrow[1 + t] = (v - mu) * rs * lng[t] + lnb[t];
    }
}

// ---------------- split-K GEMM to partial buffer (no atomics) --------------
// C_partial[slice][64][128] = A[64, kslice] @ W[kslice, 128cols]
// 128 threads: thread = (tn 0..15)x(tb 0..7), owns 8 rows x 8 cols.
// BK=16, single-buffer LDS staging with SHORT-LIVED transient regs only:
// live set during compute = 64 acc + addressing (~90 VGPR, no spill).
// PATH 0: aligned float4 W loads; PATH 1: scalar W loads w/ clamped cols.
template <int PATH>
__global__ __launch_bounds__(128, 3) void k_gemm(const float* __restrict__ A, int lda,
                                                 const float* __restrict__ W, int ldw,
                                                 float* __restrict__ P,
                                                 int N, int K, int kpb, int KS) {
    __shared__ __align__(16) float As[16 * 68];    // [kk][row], pad 68 -> 4.35 KB
    __shared__ __align__(16) float Ws[16 * 128];   // [kk][col]        -> 8 KB
    const int tid = threadIdx.x;
    const int tn = tid & 15, tb = tid >> 4;
    const int n0 = blockIdx.x * 128;
    const int kstart = blockIdx.y * kpb;
    const int kend = min(K, kstart + kpb);

    float acc[8][8];
#pragma unroll
    for (int i = 0; i < 8; ++i)
#pragma unroll
        for (int j = 0; j < 8; ++j) acc[i][j] = 0.f;

    for (int k0 = kstart; k0 < kend; k0 += 16) {
        __syncthreads();
        // stage A[0..63][k0..k0+15] -> As[kk][row]; 1024 elems / 128 thr = 8 each
#pragma unroll
        for (int u = 0; u < 8; ++u) {
            int idx = tid + 128 * u;
            int kk = idx & 15, row = idx >> 4;
            int gk = k0 + kk;
            float v = A[(size_t)row * lda + min(gk, K - 1)];
            As[kk * 68 + row] = (gk < kend) ? v : 0.f;
        }
        // stage W[k0..k0+15][n0..n0+127] -> Ws[kk][col]; 512 f4 / 128 thr = 4 each
#pragma unroll
        for (int u = 0; u < 4; ++u) {
            int f4 = tid + 128 * u;               // 0..511
            int row = f4 >> 5, col4 = f4 & 31;
            int kr = min(k0 + row, K - 1);        // A is zeroed past kend -> junk*0
            float4 wv;
            if (PATH == 0) {
                wv = *(const float4*)(W + (size_t)kr * ldw + n0 + col4 * 4);
            } else {
                const float* wr = W + (size_t)kr * ldw;
                int nb = n0 + col4 * 4;
                wv.x = wr[min(nb + 0, N - 1)];
                wv.y = wr[min(nb + 1, N - 1)];
                wv.z = wr[min(nb + 2, N - 1)];
                wv.w = wr[min(nb + 3, N - 1)];
            }
            *(float4*)&Ws[row * 128 + col4 * 4] = wv;
        }
        __syncthreads();
#pragma unroll
        for (int kk = 0; kk < 16; ++kk) {
            const float4 a0 = *(const float4*)&As[kk * 68 + tb * 8];
            const float4 a1 = *(const float4*)&As[kk * 68 + tb * 8 + 4];
            const float4 w0 = *(const float4*)&Ws[kk * 128 + tn * 8];
            const float4 w1 = *(const float4*)&Ws[kk * 128 + tn * 8 + 4];
            const float av[8] = {a0.x, a0.y, a0.z, a0.w, a1.x, a1.y, a1.z, a1.w};
            const float wv[8] = {w0.x, w0.y, w0.z, w0.w, w1.x, w1.y, w1.z, w1.w};
#pragma unroll
            for (int i = 0; i < 8; ++i)
#pragma unroll
                for (int j = 0; j < 8; ++j)
                    acc[i][j] = fmaf(av[i], wv[j], acc[i][j]);
        }
    }

    float* Pp = P + ((size_t)blockIdx.x * KS + blockIdx.y) * 8192;
#pragma unroll
    for (int i = 0; i < 8; ++i) {
        int row = tb * 8 + i;
        float4 v0 = {acc[i][0], acc[i][1], acc[i][2], acc[i][3]};
        float4 v1 = {acc[i][4], acc[i][5], acc[i][6], acc[i][7]};
        *(float4*)&Pp[row * 128 + tn * 8]     = v0;
        *(float4*)&Pp[row * 128 + tn * 8 + 4] = v1;
    }
}

// ---------------- reduce partials + bias (+gelu) ----------------
template <bool GELU>
__global__ __launch_bounds__(256) void k_reduce(const float* __restrict__ P, int KS,
                                                const float* __restrict__ bias,
                                                float* __restrict__ out, int ldo, int N) {
    int b = blockIdx.y;
    int n = blockIdx.x * 256 + threadIdx.x;
    if (n >= N) return;
    int nb = n >> 7, col = n & 127;
    const float* p = P + (size_t)nb * KS * 8192 + b * 128 + col;
    float s0 = 0.f, s1 = 0.f, s2 = 0.f, s3 = 0.f;
    int k = 0;
    for (; k + 3 < KS; k += 4) {
        s0 += p[(size_t)(k + 0) * 8192];
        s1 += p[(size_t)(k + 1) * 8192];
        s2 += p[(size_t)(k + 2) * 8192];
        s3 += p[(size_t)(k + 3) * 8192];
    }
    for (; k < KS; ++k) s0 += p[(size_t)k * 8192];
    float s = (s0 + s1) + (s2 + s3) + bias[n];
    if (GELU) s = gelu_exact(s);
    out[(size_t)b * ldo + n] = s;
}

// ---------------- LN2: one block per row (1024 cols) ----------------
__global__ __launch_bounds__(256) void k_ln2(const float* __restrict__ g1,
                                             const float* __restrict__ lng,
                                             const float* __restrict__ lnb,
                                             float* __restrict__ h2) {
    int b = blockIdx.x, tid = threadIdx.x;
    float v[4];
    float s = 0.f, s2 = 0.f;
#pragma unroll
    for (int j = 0; j < 4; ++j) {
        int nidx = tid + 256 * j;
        float x = g1[b * H4 + nidx];
        v[j] = x;
        s += x; s2 += x * x;
    }
#pragma unroll
    for (int off = 32; off > 0; off >>= 1) {
        s  += __shfl_down(s, off);
        s2 += __shfl_down(s2, off);
    }
    __shared__ float ls[4], ls2[4], smu, srs;
    int wave = tid >> 6;
    if ((tid & 63) == 0) { ls[wave] = s; ls2[wave] = s2; }
    __syncthreads();
    if (tid == 0) {
        float S  = ls[0] + ls[1] + ls[2] + ls[3];
        float S2 = ls2[0] + ls2[1] + ls2[2] + ls2[3];
        float mu = S / (float)H4;
        float var = S2 / (float)H4 - mu * mu;
        smu = mu;
        srs = rsqrtf(var + 1e-5f);
    }
    __syncthreads();
    float mu = smu, rs = srs;
#pragma unroll
    for (int j = 0; j < 4; ++j) {
        int nidx = tid + 256 * j;
        h2[b * H4 + nidx] = (v[j] - mu) * rs * lng[nidx] + lnb[nidx];
    }
}

// ---------------- launch ----------------
extern "C" void kernel_launch(void* const* d_in, const int* in_sizes, int n_in,
                              void* d_out, int out_size, void* d_ws, size_t ws_size,
                              hipStream_t stream) {
    (void)in_sizes; (void)n_in; (void)out_size;
    const int*   tags  = (const int*)d_in[0];
    const float* fc    = (const float*)d_in[1];
    const float* ln_g  = (const float*)d_in[2];
    const float* ln_b  = (const float*)d_in[3];
    const float* w1    = (const float*)d_in[4];
    const float* b1    = (const float*)d_in[5];
    const float* ln2_g = (const float*)d_in[6];
    const float* ln2_b = (const float*)d_in[7];
    const float* we1   = (const float*)d_in[8];
    const float* be1   = (const float*)d_in[9];
    const float* we2   = (const float*)d_in[10];
    const float* be2   = (const float*)d_in[11];
    const float* wd1   = (const float*)d_in[12];
    const float* bd1   = (const float*)d_in[13];
    const float* wd2   = (const float*)d_in[14];
    const float* bd2   = (const float*)d_in[15];

    float* out = (float*)d_out;
    float* y   = out;                              // 64*20001
    float* enc = out + (size_t)BATCH * NT1;        // 64*256
    float* dec = enc + BATCH * HD;                 // 64*20001

    char* ws = (char*)d_ws;
    size_t off = 0;
    int*   counts = (int*)(ws + off);   off += (size_t)BATCH * NUM_TAGS * 4;  // 5.12 MB
    float* stats  = (float*)(ws + off); off += 64 * 8 * 2 * 4;
    float* g1     = (float*)(ws + off); off += (size_t)BATCH * H4 * 4;
    float* h2     = (float*)(ws + off); off += (size_t)BATCH * H4 * 4;
    float* g2     = (float*)(ws + off); off += (size_t)BATCH * H4 * 4;
    float* dd     = (float*)(ws + off); off += (size_t)BATCH * H4 * 4;
    float* arena  = (float*)(ws + off);
    size_t avail  = (ws_size > off) ? (ws_size - off) : 0;

    // runtime split-K choice (ws_size is constant across calls -> deterministic)
    const size_t MB = 1024 * 1024;
    int KS1, KS5;
    if (avail >= 34 * MB)      { KS1 = 126; KS5 = 4; }
    else if (avail >= 21 * MB) { KS1 = 63;  KS5 = 4; }
    else if (avail >= 11 * MB) { KS1 = 31;  KS5 = 2; }
    else                       { KS1 = 31;  KS5 = 1; }
    int kpb1 = (((NT1 + KS1 - 1) / KS1) + 15) & ~15;
    int kpb5 = H4 / KS5;

    hipMemsetAsync(counts, 0, (size_t)BATCH * NUM_TAGS * 4, stream);
    k_scatter<<<32, 256, 0, stream>>>(tags, counts);
    k_ln1_stats<<<dim3(8, 64), 256, 0, stream>>>(counts, stats);
    k_ln1_apply<<<dim3(8, 64), 256, 0, stream>>>(counts, fc, ln_g, ln_b, stats, y);

    // GEMM1: y[64,20001] @ w1[20001,1024] -> partial
    k_gemm<0><<<dim3(8, KS1), 128, 0, stream>>>(y, NT1, w1, H4, arena, H4, NT1, kpb1, KS1);
    k_reduce<true><<<dim3(4, 64), 256, 0, stream>>>(arena, KS1, b1, g1, H4, H4);
    k_ln2<<<64, 256, 0, stream>>>(g1, ln2_g, ln2_b, h2);

    // GEMM2: h2 @ we1[1024,1024]
    k_gemm<0><<<dim3(8, 16), 128, 0, stream>>>(h2, H4, we1, H4, arena, H4, H4, 64, 16);
    k_reduce<true><<<dim3(4, 64), 256, 0, stream>>>(arena, 16, be1, g2, H4, H4);

    // GEMM3: g2 @ we2[1024,256]
    k_gemm<0><<<dim3(2, 16), 128, 0, stream>>>(g2, H4, we2, HD, arena, HD, H4, 64, 16);
    k_reduce<false><<<dim3(1, 64), 256, 0, stream>>>(arena, 16, be2, enc, HD, HD);

    // GEMM4: enc @ wd1[256,1024]
    k_gemm<0><<<dim3(8, 4), 128, 0, stream>>>(enc, HD, wd1, H4, arena, H4, HD, 64, 4);
    k_reduce<true><<<dim3(4, 64), 256, 0, stream>>>(arena, 4, bd1, dd, H4, H4);

    // GEMM5: dd @ wd2[1024,20001]  (odd ldw -> PATH 1)
    k_gemm<1><<<dim3(157, KS5), 128, 0, stream>>>(dd, H4, wd2, NT1, arena, NT1, H4, kpb5, KS5);
    k_reduce<false><<<dim3(79, 64), 256, 0, stream>>>(arena, KS5, bd2, dec, NT1, NT1);
}

// Round 5
// 341.118 us; speedup vs baseline: 2.4081x; 1.0955x over previous
//
#include <hip/hip_runtime.h>
#include <math.h>

#define NUM_TAGS 20000
#define BATCH 64
#define H4 1024
#define HD 256
#define NT1 20001   // NUM_TAGS + 1

__device__ __forceinline__ float gelu_exact(float x) {
    return 0.5f * x * (1.0f + erff(x * 0.7071067811865476f));
}

// ---- async global->LDS (gfx950). LDS dest = wave-uniform base + lane*size.
typedef const __attribute__((address_space(1))) void* gp_t;
typedef __attribute__((address_space(3))) void* lp_t;
__device__ __forceinline__ void async_ld4(const float* g, float* lds_base) {
    __builtin_amdgcn_global_load_lds((gp_t)g, (lp_t)lds_base, 4, 0, 0);
}
__device__ __forceinline__ void async_ld16(const float* g, float* lds_base) {
    __builtin_amdgcn_global_load_lds((gp_t)g, (lp_t)lds_base, 16, 0, 0);
}

// ---------------- counts: scatter with per-(b,f) dedup ----------------
__global__ __launch_bounds__(256) void k_scatter(const int* __restrict__ tags,
                                                 int* __restrict__ counts) {
    int g = blockIdx.x * 256 + threadIdx.x;  // (b,f)
    int b = g >> 7;
    const int* tp = tags + ((size_t)g << 4);
    int t[16];
#pragma unroll
    for (int i = 0; i < 16; ++i) t[i] = tp[i];
#pragma unroll
    for (int i = 0; i < 16; ++i) {
        bool dup = false;
        for (int j = 0; j < i; ++j) dup = dup || (t[j] == t[i]);
        if (!dup) atomicAdd(&counts[(size_t)b * NUM_TAGS + t[i]], 1);
    }
}

// ---------------- LN1 phase A: partial stats ----------------
__global__ __launch_bounds__(256) void k_ln1_stats(const int* __restrict__ counts,
                                                   float* __restrict__ stats) {
    int b = blockIdx.y, c = blockIdx.x, tid = threadIdx.x;
    const int* crow = counts + (size_t)b * NUM_TAGS;
    int lo = c * 2500, hi = lo + 2500;
    float s = 0.f, s2 = 0.f;
    for (int t = lo + tid; t < hi; t += 256) {
        float v = (float)crow[t];
        s += v; s2 += v * v;
    }
#pragma unroll
    for (int off = 32; off > 0; off >>= 1) {
        s  += __shfl_down(s, off);
        s2 += __shfl_down(s2, off);
    }
    __shared__ float ls[4], ls2[4];
    int wave = tid >> 6;
    if ((tid & 63) == 0) { ls[wave] = s; ls2[wave] = s2; }
    __syncthreads();
    if (tid == 0) {
        stats[(b * 8 + c) * 2 + 0] = ls[0] + ls[1] + ls[2] + ls[3];
        stats[(b * 8 + c) * 2 + 1] = ls2[0] + ls2[1] + ls2[2] + ls2[3];
    }
}

// ---------------- LN1 phase B: apply ----------------
__global__ __launch_bounds__(256) void k_ln1_apply(const int* __restrict__ counts,
                                                   const float* __restrict__ fc,
                                                   const float* __restrict__ lng,
                                                   const float* __restrict__ lnb,
                                                   const float* __restrict__ stats,
                                                   float* __restrict__ y) {
    int b = blockIdx.y, c = blockIdx.x, tid = threadIdx.x;
    float S = 0.f, S2 = 0.f;
#pragma unroll
    for (int i = 0; i < 8; ++i) {
        S  += stats[(b * 8 + i) * 2 + 0];
        S2 += stats[(b * 8 + i) * 2 + 1];
    }
    float mu = S / (float)NUM_TAGS;
    float var = S2 / (float)NUM_TAGS - mu * mu;
    float rs = rsqrtf(var + 1e-5f);
    const int* crow = counts + (size_t)b * NUM_TAGS;
    float* yrow = y + (size_t)b * NT1;
    if (c == 0 && tid == 0) yrow[0] = fc[b] * 0.01f;
    int lo = c * 2500, hi = lo + 2500;
    for (int t = lo + tid; t < hi; t += 256) {
        float v = (float)crow[t];
        yrow[1 + t] = (v - mu) * rs * lng[t] + lnb[t];
    }
}

// ---------------- async double-buffered split-K GEMM -----------------------
// P[(bx*KS+ky)][64][256] = A[64, kslice] @ W[kslice, 256cols]
// 256 thr: tn=tid&31 (8 cols each), tb=tid>>5 (8 rows each). BK=16.
// Requires: kpb % 16 == 0, (kend-kstart) % 16 == 0. No clamping on K.
// PATH 0: W rows 16B-aligned (ldw%4==0, N%256==0). PATH 1: dword W loads,
// col clamped to N-1 (odd ldw ok).
template <int PATH>
__global__ __launch_bounds__(256, 2) void k_gemm(const float* __restrict__ A, int lda,
                                                 const float* __restrict__ W, int ldw,
                                                 float* __restrict__ P,
                                                 int N, int kpb) {
    __shared__ __align__(16) float As[2][1024];   // [row][kk] : row*16 + kk
    __shared__ __align__(16) float Ws[2][4096];   // [kk][col] : kk*256 + col
    const int tid = threadIdx.x;
    const int lane = tid & 63, wid = tid >> 6;
    const int tn = tid & 31, tb = tid >> 5;
    const int n0 = blockIdx.x * 256;
    const int kstart = blockIdx.y * kpb;
    const int nchunk = kpb >> 4;   // all slices full (kpb*gridDim.y == K)

    float acc[8][8];
#pragma unroll
    for (int i = 0; i < 8; ++i)
#pragma unroll
        for (int j = 0; j < 8; ++j) acc[i][j] = 0.f;

    // ---- issue chunk starting at k0 into buffer b (async DMA) ----
    auto issue = [&](int b, int k0) {
        // A tile: 64x16 = 1024 dwords; d -> row=d>>4, kk=d&15
#pragma unroll
        for (int j = 0; j < 4; ++j) {
            int d0 = (wid * 4 + j) * 64;
            int d = d0 + lane;
            int r = d >> 4, kk = d & 15;
            async_ld4(A + (size_t)r * lda + k0 + kk, &As[b][d0]);
        }
        if (PATH == 0) {
            // W tile: 16 rows x 256 cols = 1024 16B-granules; g -> kk=g>>6, c4=g&63
#pragma unroll
            for (int j = 0; j < 4; ++j) {
                int g0 = (wid * 4 + j) * 64;
                int g = g0 + lane;
                int kk = g >> 6, c4 = g & 63;
                async_ld16(W + (size_t)(k0 + kk) * ldw + n0 + c4 * 4, &Ws[b][g0 * 4]);
            }
        } else {
            // W tile: 4096 dwords; d -> kk=d>>8, c=d&255 (col clamped)
#pragma unroll
            for (int j = 0; j < 16; ++j) {
                int d0 = (wid * 16 + j) * 64;
                int d = d0 + lane;
                int kk = d >> 8, c = d & 255;
                async_ld4(W + (size_t)(k0 + kk) * ldw + min(n0 + c, N - 1), &Ws[b][d0]);
            }
        }
    };

    issue(0, kstart);
    for (int c = 0; c < nchunk; ++c) {
        __syncthreads();                 // drains vmcnt -> buf[c&1] ready
        if (c + 1 < nchunk) issue((c + 1) & 1, kstart + 16 * (c + 1));
        const float* Ab = As[c & 1];
        const float* Wb = Ws[c & 1];
#pragma unroll
        for (int k4 = 0; k4 < 4; ++k4) {
            float4 a4[8];
#pragma unroll
            for (int i = 0; i < 8; ++i)
                a4[i] = *(const float4*)&Ab[(tb * 8 + i) * 16 + k4 * 4];
#pragma unroll
            for (int kl = 0; kl < 4; ++kl) {
                const float4 w0 = *(const float4*)&Wb[(k4 * 4 + kl) * 256 + tn * 8];
                const float4 w1 = *(const float4*)&Wb[(k4 * 4 + kl) * 256 + tn * 8 + 4];
                const float wv[8] = {w0.x, w0.y, w0.z, w0.w, w1.x, w1.y, w1.z, w1.w};
#pragma unroll
                for (int i = 0; i < 8; ++i) {
                    float av = (kl == 0) ? a4[i].x : (kl == 1) ? a4[i].y
                             : (kl == 2) ? a4[i].z : a4[i].w;
#pragma unroll
                    for (int jj = 0; jj < 8; ++jj)
                        acc[i][jj] = fmaf(av, wv[jj], acc[i][jj]);
                }
            }
        }
    }

    float* Pp = P + ((size_t)blockIdx.x * gridDim.y + blockIdx.y) * 16384;
#pragma unroll
    for (int i = 0; i < 8; ++i) {
        int row = tb * 8 + i;
        float4 v0 = {acc[i][0], acc[i][1], acc[i][2], acc[i][3]};
        float4 v1 = {acc[i][4], acc[i][5], acc[i][6], acc[i][7]};
        *(float4*)&Pp[row * 256 + tn * 8]     = v0;
        *(float4*)&Pp[row * 256 + tn * 8 + 4] = v1;
    }
}

// ---------------- reduce partials + bias (+rank-1 fc term) (+gelu) ---------
template <bool GELU>
__global__ __launch_bounds__(256) void k_reduce(const float* __restrict__ P, int KS,
                                                const float* __restrict__ bias,
                                                const float* __restrict__ r1row,
                                                const float* __restrict__ fc,
                                                float* __restrict__ out, int ldo, int N) {
    int b = blockIdx.y;
    int n = blockIdx.x * 256 + threadIdx.x;
    if (n >= N) return;
    int nb = n >> 8, col = n & 255;
    const float* p = P + (size_t)nb * KS * 16384 + b * 256 + col;
    float s0 = 0.f, s1 = 0.f, s2 = 0.f, s3 = 0.f;
    int k = 0;
    for (; k + 3 < KS; k += 4) {
        s0 += p[(size_t)(k + 0) * 16384];
        s1 += p[(size_t)(k + 1) * 16384];
        s2 += p[(size_t)(k + 2) * 16384];
        s3 += p[(size_t)(k + 3) * 16384];
    }
    for (; k < KS; ++k) s0 += p[(size_t)k * 16384];
    float s = (s0 + s1) + (s2 + s3) + bias[n];
    if (r1row) s += fc[b] * 0.01f * r1row[n];
    if (GELU) s = gelu_exact(s);
    out[(size_t)b * ldo + n] = s;
}

// ---------------- LN2: one block per row (1024 cols) ----------------
__global__ __launch_bounds__(256) void k_ln2(const float* __restrict__ g1,
                                             const float* __restrict__ lng,
                                             const float* __restrict__ lnb,
                                             float* __restrict__ h2) {
    int b = blockIdx.x, tid = threadIdx.x;
    float v[4];
    float s = 0.f, s2 = 0.f;
#pragma unroll
    for (int j = 0; j < 4; ++j) {
        int nidx = tid + 256 * j;
        float x = g1[b * H4 + nidx];
        v[j] = x;
        s += x; s2 += x * x;
    }
#pragma unroll
    for (int off = 32; off > 0; off >>= 1) {
        s  += __shfl_down(s, off);
        s2 += __shfl_down(s2, off);
    }
    __shared__ float ls[4], ls2[4], smu, srs;
    int wave = tid >> 6;
    if ((tid & 63) == 0) { ls[wave] = s; ls2[wave] = s2; }
    __syncthreads();
    if (tid == 0) {
        float S  = ls[0] + ls[1] + ls[2] + ls[3];
        float S2 = ls2[0] + ls2[1] + ls2[2] + ls2[3];
        float mu = S / (float)H4;
        float var = S2 / (float)H4 - mu * mu;
        smu = mu;
        srs = rsqrtf(var + 1e-5f);
    }
    __syncthreads();
    float mu = smu, rs = srs;
#pragma unroll
    for (int j = 0; j < 4; ++j) {
        int nidx = tid + 256 * j;
        h2[b * H4 + nidx] = (v[j] - mu) * rs * lng[nidx] + lnb[nidx];
    }
}

// ---------------- launch ----------------
extern "C" void kernel_launch(void* const* d_in, const int* in_sizes, int n_in,
                              void* d_out, int out_size, void* d_ws, size_t ws_size,
                              hipStream_t stream) {
    (void)in_sizes; (void)n_in; (void)out_size;
    const int*   tags  = (const int*)d_in[0];
    const float* fc    = (const float*)d_in[1];
    const float* ln_g  = (const float*)d_in[2];
    const float* ln_b  = (const float*)d_in[3];
    const float* w1    = (const float*)d_in[4];
    const float* b1    = (const float*)d_in[5];
    const float* ln2_g = (const float*)d_in[6];
    const float* ln2_b = (const float*)d_in[7];
    const float* we1   = (const float*)d_in[8];
    const float* be1   = (const float*)d_in[9];
    const float* we2   = (const float*)d_in[10];
    const float* be2   = (const float*)d_in[11];
    const float* wd1   = (const float*)d_in[12];
    const float* bd1   = (const float*)d_in[13];
    const float* wd2   = (const float*)d_in[14];
    const float* bd2   = (const float*)d_in[15];

    float* out = (float*)d_out;
    float* y   = out;                              // 64*20001
    float* enc = out + (size_t)BATCH * NT1;        // 64*256
    float* dec = enc + BATCH * HD;                 // 64*20001

    char* ws = (char*)d_ws;
    size_t off = 0;
    int*   counts = (int*)(ws + off);   off += (size_t)BATCH * NUM_TAGS * 4;  // 5.12 MB
    float* stats  = (float*)(ws + off); off += 64 * 8 * 2 * 4;
    float* g1     = (float*)(ws + off); off += (size_t)BATCH * H4 * 4;
    float* h2     = (float*)(ws + off); off += (size_t)BATCH * H4 * 4;
    float* g2     = (float*)(ws + off); off += (size_t)BATCH * H4 * 4;
    float* dd     = (float*)(ws + off); off += (size_t)BATCH * H4 * 4;
    float* arena  = (float*)(ws + off);
    size_t avail  = (ws_size > off) ? (ws_size - off) : 0;

    // split-K tiers (ws_size constant across calls -> deterministic)
    const size_t MB = 1024 * 1024;
    int KS1, KS5;
    if (avail >= 45 * MB)      { KS1 = 125; KS5 = 8; }   // arenas 32.8 / 41.4 MB
    else if (avail >= 33 * MB) { KS1 = 125; KS5 = 4; }
    else if (avail >= 17 * MB) { KS1 = 63;  KS5 = 4; }
    else                       { KS1 = 63;  KS5 = 2; }
    int kpb1 = 20000 / KS1;          // 160 or 320 (both %16==0; KS1*kpb1==20000 for 125)
    if (KS1 == 63) kpb1 = 320;       // 63*320 = 20160 >= 20000; last block short but %16
    int kpb5 = H4 / KS5;

    hipMemsetAsync(counts, 0, (size_t)BATCH * NUM_TAGS * 4, stream);
    k_scatter<<<32, 256, 0, stream>>>(tags, counts);
    k_ln1_stats<<<dim3(8, 64), 256, 0, stream>>>(counts, stats);
    k_ln1_apply<<<dim3(8, 64), 256, 0, stream>>>(counts, fc, ln_g, ln_b, stats, y);

    // GEMM1: yn[64,20000] @ w1[1:,1024]; fc-column folded into reduce as rank-1
    if (KS1 == 125) {
        k_gemm<0><<<dim3(4, 125), 256, 0, stream>>>(y + 1, NT1, w1 + H4, H4, arena, H4, 160);
        k_reduce<true><<<dim3(4, 64), 256, 0, stream>>>(arena, 125, b1, w1, fc, g1, H4, H4);
    } else {
        // KS1=63: last slice is 20000-62*320=160 (still %16). Pad via kpb trick:
        // use uniform kpb=320 but 63rd block would read past K -> instead launch 62 full
        // slices of 320 plus fold the final 160 into slice 61? Simpler: 125 slices of 160.
        k_gemm<0><<<dim3(4, 125), 256, 0, stream>>>(y + 1, NT1, w1 + H4, H4, arena, H4, 160);
        k_reduce<true><<<dim3(4, 64), 256, 0, stream>>>(arena, 125, b1, w1, fc, g1, H4, H4);
    }
    k_ln2<<<64, 256, 0, stream>>>(g1, ln2_g, ln2_b, h2);

    // GEMM2: h2 @ we1[1024,1024]
    k_gemm<0><<<dim3(4, 32), 256, 0, stream>>>(h2, H4, we1, H4, arena, H4, 32);
    k_reduce<true><<<dim3(4, 64), 256, 0, stream>>>(arena, 32, be1, nullptr, nullptr, g2, H4, H4);

    // GEMM3: g2 @ we2[1024,256]
    k_gemm<0><<<dim3(1, 32), 256, 0, stream>>>(g2, H4, we2, HD, arena, HD, 32);
    k_reduce<false><<<dim3(1, 64), 256, 0, stream>>>(arena, 32, be2, nullptr, nullptr, enc, HD, HD);

    // GEMM4: enc @ wd1[256,1024]
    k_gemm<0><<<dim3(4, 16), 256, 0, stream>>>(enc, HD, wd1, H4, arena, H4, 16);
    k_reduce<true><<<dim3(4, 64), 256, 0, stream>>>(arena, 16, bd1, nullptr, nullptr, dd, H4, H4);

    // GEMM5: dd @ wd2[1024,20001]  (odd ldw -> PATH 1)
    k_gemm<1><<<dim3(79, KS5), 256, 0, stream>>>(dd, H4, wd2, NT1, arena, NT1, kpb5);
    k_reduce<false><<<dim3(79, 64), 256, 0, stream>>>(arena, KS5, bd2, nullptr, nullptr, dec, NT1, NT1);
}